// Round 3
// baseline (140.937 us; speedup 1.0000x reference)
//
#include <hip/hip_runtime.h>
#include <hip/hip_bf16.h>

#define LQ 4096
#define DD 64
#define NB 4
#define NTOT ((size_t)NB * LQ * DD)

typedef __attribute__((ext_vector_type(4))) float f32x4;
typedef __attribute__((ext_vector_type(8))) short short8;
typedef __attribute__((ext_vector_type(2))) unsigned int uint2v;
typedef __attribute__((ext_vector_type(4))) unsigned short ushort4v;

static __device__ __forceinline__ unsigned short f2bf(float x) {
  __hip_bfloat16 h = __float2bfloat16(x);
  return __builtin_bit_cast(unsigned short, h);
}
static __device__ __forceinline__ float ex2(float x) { return __builtin_amdgcn_exp2f(x); }

// score scale folded into log2 domain: s2 = T * (0.125 * log2(e))
#define C1 0.18033688011112042f

// ---------------------------------------------------------------------------
// prep: Q,K -> bf16 row-major [b][i][d]; V -> bf16 transposed Vt[b][d][i]
// grid: NB*256 blocks (16-row tiles) of 256 -> 4 blocks/CU
// ---------------------------------------------------------------------------
__global__ __launch_bounds__(256) void prep_kernel(
    const float* __restrict__ q, const float* __restrict__ k,
    const float* __restrict__ v,
    unsigned short* __restrict__ Qb, unsigned short* __restrict__ Kb,
    unsigned short* __restrict__ Vt)
{
  __shared__ unsigned short vt[16][68];
  const int bx = blockIdx.x;
  const int b = bx >> 8, t = bx & 255;
  const int i0 = t << 4;
  const int tid = threadIdx.x;
  const int r = tid >> 4, c = (tid & 15) << 2;
  const int rowbase = (b * LQ + i0 + r) * DD + c;
  const f32x4 qv = *(const f32x4*)(q + rowbase);
  const f32x4 kv = *(const f32x4*)(k + rowbase);
  const f32x4 vv = *(const f32x4*)(v + rowbase);
  ushort4v qo = { f2bf(qv[0]), f2bf(qv[1]), f2bf(qv[2]), f2bf(qv[3]) };
  ushort4v ko = { f2bf(kv[0]), f2bf(kv[1]), f2bf(kv[2]), f2bf(kv[3]) };
  ushort4v vo = { f2bf(vv[0]), f2bf(vv[1]), f2bf(vv[2]), f2bf(vv[3]) };
  *(ushort4v*)(Qb + rowbase) = qo;
  *(ushort4v*)(Kb + rowbase) = ko;
  *(ushort4v*)(&vt[r][c]) = vo;
  __syncthreads();
  const int d = tid >> 2, ic = (tid & 3) << 2;
  ushort4v o = { vt[ic + 0][d], vt[ic + 1][d], vt[ic + 2][d], vt[ic + 3][d] };
  *(ushort4v*)(Vt + (b * DD + d) * LQ + i0 + ic) = o;
}

// ---------------------------------------------------------------------------
// stats: c2[b][i] = log2( sum_j exp2(T[i,j]*C1) )  (scores bounded, no max)
// grid: NB*256 blocks of 512 (8 waves, j split 8-ways) -> 32 waves/CU
// ---------------------------------------------------------------------------
__global__ __launch_bounds__(512, 8) void stats_kernel(
    const unsigned short* __restrict__ Qb, const unsigned short* __restrict__ Kb,
    float* __restrict__ c2g)
{
  const int bx = blockIdx.x;
  const int b = bx >> 8, it = bx & 255;
  const int i0 = it << 4;
  const int tid = threadIdx.x;
  const int w = tid >> 6;
  const int lane = tid & 63;
  const int l15 = lane & 15, g = lane >> 4;

  const unsigned short* qrow = Qb + (b * LQ + i0 + l15) * DD + g * 8;
  const short8 aq0 = *(const short8*)(qrow);
  const short8 aq1 = *(const short8*)(qrow + 32);

  float ls[4] = {0.f, 0.f, 0.f, 0.f};

  const int j0 = w << 9;
  const unsigned short* kbase = Kb + (b * LQ + j0 + l15) * DD + g * 8;
  for (int s = 0; s < 32; ++s) {
    const unsigned short* kr = kbase + s * 16 * DD;
    const short8 bk0 = *(const short8*)(kr);
    const short8 bk1 = *(const short8*)(kr + 32);
    f32x4 accv = __builtin_amdgcn_mfma_f32_16x16x32_bf16(
        aq0, bk0, (f32x4){0.f, 0.f, 0.f, 0.f}, 0, 0, 0);
    accv = __builtin_amdgcn_mfma_f32_16x16x32_bf16(aq1, bk1, accv, 0, 0, 0);
#pragma unroll
    for (int qq = 0; qq < 4; ++qq) ls[qq] += ex2(accv[qq] * C1);
  }
#pragma unroll
  for (int mask = 1; mask <= 8; mask <<= 1)
#pragma unroll
    for (int qq = 0; qq < 4; ++qq) ls[qq] += __shfl_xor(ls[qq], mask, 64);

  __shared__ float sl[8][16];
  if (l15 == 0) {
#pragma unroll
    for (int qq = 0; qq < 4; ++qq) sl[w][g * 4 + qq] = ls[qq];
  }
  __syncthreads();
  if (tid < 16) {
    float l = 0.f;
#pragma unroll
    for (int ww = 0; ww < 8; ++ww) l += sl[ww][tid];
    c2g[b * LQ + i0 + tid] = __builtin_amdgcn_logf(l);  // v_log_f32 = log2
  }
}

// ---------------------------------------------------------------------------
// output: dst[j][d] (+cs chunk) = sum_{i in chunk} exp2(T[j,i]*C1-c2[i])*v[i][d]
// grid: NB*128*SPLIT blocks of 256; 4 waves split the chunk's i 4-ways,
// LDS-reduced, stored fp32 (to out if SPLIT==1 else to partial[cs]).
// ---------------------------------------------------------------------------
template<int SPLIT, int ITERS>
__global__ __launch_bounds__(256, 4) void attn_out_kernel(
    const unsigned short* __restrict__ Qb, const unsigned short* __restrict__ Kb,
    const unsigned short* __restrict__ Vt, const float* __restrict__ c2g,
    float* __restrict__ dst)
{
  __shared__ __align__(16) unsigned short Pall[4][1024]; // per-wave [2 js][32 i][16 jlow]
  __shared__ float red[4][2048];                         // per-wave 32j x 64d partials

  const int bx = blockIdx.x;
  const int cs = bx & (SPLIT - 1);
  const int jt = (bx / SPLIT) & 127;
  const int b = bx / (SPLIT * 128);
  const int j0 = jt << 5;
  const int tid = threadIdx.x;
  const int w = tid >> 6;
  const int lane = tid & 63;
  const int l15 = lane & 15, g = lane >> 4;

  const unsigned Pbase = (unsigned)(size_t)(&Pall[w][0]);

  // resident K A-frags: A[m=jlocal=l15][k=d], 2 jsub x 2 d-halves
  short8 ka[2][2];
#pragma unroll
  for (int js = 0; js < 2; ++js)
#pragma unroll
    for (int dh = 0; dh < 2; ++dh)
      ka[js][dh] = *(const short8*)(Kb + (b * LQ + j0 + js * 16 + l15) * DD + dh * 32 + g * 8);

  f32x4 acc[2][4];
#pragma unroll
  for (int js = 0; js < 2; ++js)
#pragma unroll
    for (int ds = 0; ds < 4; ++ds)
      acc[js][ds] = (f32x4){0.f, 0.f, 0.f, 0.f};

  const float* c2b = c2g + b * LQ;
  const unsigned short* Qbase = Qb + b * LQ * DD;
  const unsigned short* Vbase = Vt + b * DD * LQ;
  const int ibase = (cs * 4 + w) * (1024 / SPLIT);

#pragma unroll 2
  for (int itr = 0; itr < ITERS; ++itr) {
    const int i0 = ibase + (itr << 5);
    // Q B-frags: B[k=d][n=ilocal=l15]
    short8 qf[2][2];
#pragma unroll
    for (int is = 0; is < 2; ++is)
#pragma unroll
      for (int dh = 0; dh < 2; ++dh)
        qf[is][dh] = *(const short8*)(Qbase + (i0 + is * 16 + l15) * DD + dh * 32 + g * 8);
    // V B-frags: B[k=i][n=d=l15] from transposed Vt
    short8 vf[4];
#pragma unroll
    for (int ds = 0; ds < 4; ++ds)
      vf[ds] = *(const short8*)(Vbase + (ds * 16 + l15) * LQ + i0 + g * 8);
    const float cc0 = c2b[i0 + l15];
    const float cc1 = c2b[i0 + 16 + l15];

    // T = K_j . Q_i^T ; P = exp2(T*C1 - c2[i]) ; store [i][jlow] to LDS
#pragma unroll
    for (int js = 0; js < 2; ++js) {
#pragma unroll
      for (int is = 0; is < 2; ++is) {
        f32x4 tt = __builtin_amdgcn_mfma_f32_16x16x32_bf16(
            ka[js][0], qf[is][0], (f32x4){0.f, 0.f, 0.f, 0.f}, 0, 0, 0);
        tt = __builtin_amdgcn_mfma_f32_16x16x32_bf16(ka[js][1], qf[is][1], tt, 0, 0, 0);
        const float cI = is ? cc1 : cc0;
        const float p0 = ex2(tt[0] * C1 - cI);
        const float p1 = ex2(tt[1] * C1 - cI);
        const float p2 = ex2(tt[2] * C1 - cI);
        const float p3 = ex2(tt[3] * C1 - cI);
        uint2v uu;
        uu[0] = (unsigned)f2bf(p0) | ((unsigned)f2bf(p1) << 16);
        uu[1] = (unsigned)f2bf(p2) | ((unsigned)f2bf(p3) << 16);
        *(uint2v*)(&Pall[w][(js * 32 + is * 16 + l15) * 16 + g * 4]) = uu;
      }
    }

    // transpose-read P^T A-frags and accumulate PV
#pragma unroll
    for (int js = 0; js < 2; ++js) {
      const unsigned a = Pbase + js * 1024 + g * 256 + l15 * 8;
      unsigned long long r0, r1;
      asm volatile("ds_read_b64_tr_b16 %0, %1" : "=v"(r0) : "v"(a) : "memory");
      asm volatile("ds_read_b64_tr_b16 %0, %1 offset:128" : "=v"(r1) : "v"(a) : "memory");
      asm volatile("s_waitcnt lgkmcnt(0)" ::: "memory");
      __builtin_amdgcn_sched_barrier(0);
      union { unsigned long long u[2]; short8 s; } pa;
      pa.u[0] = r0; pa.u[1] = r1;
#pragma unroll
      for (int ds = 0; ds < 4; ++ds)
        acc[js][ds] = __builtin_amdgcn_mfma_f32_16x16x32_bf16(pa.s, vf[ds], acc[js][ds], 0, 0, 0);
    }
  }

  // per-wave partials -> LDS, cross-wave sum, fp32 store
#pragma unroll
  for (int js = 0; js < 2; ++js)
#pragma unroll
    for (int ds = 0; ds < 4; ++ds)
#pragma unroll
      for (int qq = 0; qq < 4; ++qq)
        red[w][(js * 16 + g * 4 + qq) * 64 + ds * 16 + l15] = acc[js][ds][qq];
  __syncthreads();

  const int jl = tid >> 3;
  const int d0 = (tid & 7) << 3;
  f32x4 o0, o1;
#pragma unroll
  for (int e = 0; e < 4; ++e) {
    const int idx = jl * 64 + d0 + e;
    o0[e] = red[0][idx] + red[1][idx] + red[2][idx] + red[3][idx];
  }
#pragma unroll
  for (int e = 0; e < 4; ++e) {
    const int idx = jl * 64 + d0 + 4 + e;
    o1[e] = red[0][idx] + red[1][idx] + red[2][idx] + red[3][idx];
  }
  float* op = dst + (SPLIT > 1 ? (size_t)cs * NTOT : 0) +
              (b * LQ + j0 + jl) * DD + d0;
  *(f32x4*)(op) = o0;
  *(f32x4*)(op + 4) = o1;
}

// ---------------------------------------------------------------------------
// reduce: out = sum over SPLIT chunks of partial
// ---------------------------------------------------------------------------
template<int SPLIT>
__global__ __launch_bounds__(256) void reduce_kernel(
    const float* __restrict__ part, float* __restrict__ out)
{
  const size_t idx = ((size_t)blockIdx.x * 256 + threadIdx.x) * 4;
  f32x4 s = *(const f32x4*)(part + idx);
#pragma unroll
  for (int c = 1; c < SPLIT; ++c) {
    const f32x4 t = *(const f32x4*)(part + idx + (size_t)c * NTOT);
    s[0] += t[0]; s[1] += t[1]; s[2] += t[2]; s[3] += t[3];
  }
  *(f32x4*)(out + idx) = s;
}

// ---------------------------------------------------------------------------
extern "C" void kernel_launch(void* const* d_in, const int* in_sizes, int n_in,
                              void* d_out, int out_size, void* d_ws, size_t ws_size,
                              hipStream_t stream) {
  const float* q = (const float*)d_in[0];
  const float* k = (const float*)d_in[1];
  const float* v = (const float*)d_in[2];

  unsigned short* Qb = (unsigned short*)d_ws;
  unsigned short* Kb = Qb + NTOT;
  unsigned short* Vt = Kb + NTOT;
  float* c2 = (float*)(Vt + NTOT);
  float* partial = c2 + (size_t)NB * LQ;
  float* outp = (float*)d_out;

  const size_t base = 3 * NTOT * 2 + (size_t)NB * LQ * 4;
  const size_t per = NTOT * 4;

  prep_kernel<<<NB * 256, 256, 0, stream>>>(q, k, v, Qb, Kb, Vt);
  stats_kernel<<<NB * 256, 512, 0, stream>>>(Qb, Kb, c2);

  if (ws_size >= base + 4 * per) {
    attn_out_kernel<4, 8><<<NB * 128 * 4, 256, 0, stream>>>(Qb, Kb, Vt, c2, partial);
    reduce_kernel<4><<<(int)(NTOT / 1024), 256, 0, stream>>>(partial, outp);
  } else if (ws_size >= base + 2 * per) {
    attn_out_kernel<2, 16><<<NB * 128 * 2, 256, 0, stream>>>(Qb, Kb, Vt, c2, partial);
    reduce_kernel<2><<<(int)(NTOT / 1024), 256, 0, stream>>>(partial, outp);
  } else {
    attn_out_kernel<1, 32><<<NB * 128, 256, 0, stream>>>(Qb, Kb, Vt, c2, outp);
  }
}

// Round 4
// 111.262 us; speedup vs baseline: 1.2667x; 1.2667x over previous
//
#include <hip/hip_runtime.h>
#include <hip/hip_bf16.h>

#define LQ 4096
#define DD 64
#define NB 4
#define NTOT ((size_t)NB * LQ * DD)

typedef __attribute__((ext_vector_type(4))) float f32x4;
typedef __attribute__((ext_vector_type(8))) short short8;
typedef __attribute__((ext_vector_type(2))) unsigned int uint2v;
typedef __attribute__((ext_vector_type(4))) unsigned short ushort4v;

static __device__ __forceinline__ unsigned short f2bf(float x) {
  __hip_bfloat16 h = __float2bfloat16(x);
  return __builtin_bit_cast(unsigned short, h);
}
static __device__ __forceinline__ float ex2(float x) { return __builtin_amdgcn_exp2f(x); }

// score scale folded into log2 domain: s2 = T * (0.125 * log2(e))
#define C1 0.18033688011112042f

// ---------------------------------------------------------------------------
// prep: Q,K -> bf16 row-major [b][i][d]; V -> bf16 transposed Vt[b][d][i]
// ---------------------------------------------------------------------------
__global__ __launch_bounds__(256) void prep_kernel(
    const float* __restrict__ q, const float* __restrict__ k,
    const float* __restrict__ v,
    unsigned short* __restrict__ Qb, unsigned short* __restrict__ Kb,
    unsigned short* __restrict__ Vt)
{
  __shared__ unsigned short vt[16][68];
  const int bx = blockIdx.x;
  const int b = bx >> 8, t = bx & 255;
  const int i0 = t << 4;
  const int tid = threadIdx.x;
  const int r = tid >> 4, c = (tid & 15) << 2;
  const int rowbase = (b * LQ + i0 + r) * DD + c;
  const f32x4 qv = *(const f32x4*)(q + rowbase);
  const f32x4 kv = *(const f32x4*)(k + rowbase);
  const f32x4 vv = *(const f32x4*)(v + rowbase);
  ushort4v qo = { f2bf(qv[0]), f2bf(qv[1]), f2bf(qv[2]), f2bf(qv[3]) };
  ushort4v ko = { f2bf(kv[0]), f2bf(kv[1]), f2bf(kv[2]), f2bf(kv[3]) };
  ushort4v vo = { f2bf(vv[0]), f2bf(vv[1]), f2bf(vv[2]), f2bf(vv[3]) };
  *(ushort4v*)(Qb + rowbase) = qo;
  *(ushort4v*)(Kb + rowbase) = ko;
  *(ushort4v*)(&vt[r][c]) = vo;
  __syncthreads();
  const int d = tid >> 2, ic = (tid & 3) << 2;
  ushort4v o = { vt[ic + 0][d], vt[ic + 1][d], vt[ic + 2][d], vt[ic + 3][d] };
  *(ushort4v*)(Vt + (b * DD + d) * LQ + i0 + ic) = o;
}

// ---------------------------------------------------------------------------
// stats: c2[b][i] = log2( sum_j exp2(T[i,j]*C1) )  (scores bounded, no max)
// grid: NB*128 blocks of 512; block owns 32 rows (2 A-frags), 8 waves split j
// ---------------------------------------------------------------------------
__global__ __launch_bounds__(512, 4) void stats_kernel(
    const unsigned short* __restrict__ Qb, const unsigned short* __restrict__ Kb,
    float* __restrict__ c2g)
{
  const int bx = blockIdx.x;
  const int b = bx >> 7, it = bx & 127;
  const int i0 = it << 5;
  const int tid = threadIdx.x;
  const int w = tid >> 6;
  const int lane = tid & 63;
  const int l15 = lane & 15, g = lane >> 4;

  const unsigned short* qrow = Qb + (b * LQ + i0 + l15) * DD + g * 8;
  short8 aq[2][2];
  aq[0][0] = *(const short8*)(qrow);
  aq[0][1] = *(const short8*)(qrow + 32);
  aq[1][0] = *(const short8*)(qrow + 16 * DD);
  aq[1][1] = *(const short8*)(qrow + 16 * DD + 32);

  float ls[2][4] = {{0.f,0.f,0.f,0.f},{0.f,0.f,0.f,0.f}};

  const int j0 = w << 9;
  const unsigned short* kbase = Kb + (b * LQ + j0 + l15) * DD + g * 8;
  for (int s = 0; s < 32; ++s) {
    const unsigned short* kr = kbase + s * 16 * DD;
    const short8 bk0 = *(const short8*)(kr);
    const short8 bk1 = *(const short8*)(kr + 32);
#pragma unroll
    for (int f = 0; f < 2; ++f) {
      f32x4 accv = __builtin_amdgcn_mfma_f32_16x16x32_bf16(
          aq[f][0], bk0, (f32x4){0.f, 0.f, 0.f, 0.f}, 0, 0, 0);
      accv = __builtin_amdgcn_mfma_f32_16x16x32_bf16(aq[f][1], bk1, accv, 0, 0, 0);
#pragma unroll
      for (int qq = 0; qq < 4; ++qq) ls[f][qq] += ex2(accv[qq] * C1);
    }
  }
#pragma unroll
  for (int mask = 1; mask <= 8; mask <<= 1)
#pragma unroll
    for (int f = 0; f < 2; ++f)
#pragma unroll
      for (int qq = 0; qq < 4; ++qq) ls[f][qq] += __shfl_xor(ls[f][qq], mask, 64);

  __shared__ float sl[8][32];
  if (l15 == 0) {
#pragma unroll
    for (int f = 0; f < 2; ++f)
#pragma unroll
      for (int qq = 0; qq < 4; ++qq) sl[w][f * 16 + g * 4 + qq] = ls[f][qq];
  }
  __syncthreads();
  if (tid < 32) {
    float l = 0.f;
#pragma unroll
    for (int ww = 0; ww < 8; ++ww) l += sl[ww][tid];
    c2g[b * LQ + i0 + tid] = __builtin_amdgcn_logf(l);  // v_log_f32 = log2
  }
}

// ---------------------------------------------------------------------------
// output: dst[j][d] (+cs chunk) = sum_{i in chunk} exp2(T[j,i]*C1-c2[i])*v[i][d]
// Software-pipelined: Q-frags/c2 double-buffered (prefetch), V loaded at iter
// top; single tr-read asm (4 reads + wait, dataflow-anchored outputs).
// ---------------------------------------------------------------------------
template<int SPLIT, int ITERS>
__global__ __launch_bounds__(256, 4) void attn_out_kernel(
    const unsigned short* __restrict__ Qb, const unsigned short* __restrict__ Kb,
    const unsigned short* __restrict__ Vt, const float* __restrict__ c2g,
    float* __restrict__ dst)
{
  __shared__ __align__(16) unsigned short Pall[4][1024]; // per-wave [2 js][32 i][16 jlow]
  __shared__ float red[4][2048];                         // per-wave 32j x 64d partials

  const int bx = blockIdx.x;
  const int cs = bx & (SPLIT - 1);
  const int jt = (bx / SPLIT) & 127;
  const int b = bx / (SPLIT * 128);
  const int j0 = jt << 5;
  const int tid = threadIdx.x;
  const int w = tid >> 6;
  const int lane = tid & 63;
  const int l15 = lane & 15, g = lane >> 4;

  const unsigned Pbase = (unsigned)(size_t)(&Pall[w][0]);

  // resident K A-frags: A[m=jlocal=l15][k=d], 2 jsub x 2 d-halves
  short8 ka[2][2];
#pragma unroll
  for (int js = 0; js < 2; ++js)
#pragma unroll
    for (int dh = 0; dh < 2; ++dh)
      ka[js][dh] = *(const short8*)(Kb + (b * LQ + j0 + js * 16 + l15) * DD + dh * 32 + g * 8);

  f32x4 acc[2][4];
#pragma unroll
  for (int js = 0; js < 2; ++js)
#pragma unroll
    for (int ds = 0; ds < 4; ++ds)
      acc[js][ds] = (f32x4){0.f, 0.f, 0.f, 0.f};

  const float* c2b = c2g + b * LQ;
  const unsigned short* Qbase = Qb + b * LQ * DD;
  const unsigned short* Vbase = Vt + b * DD * LQ;
  const int ibase = (cs * 4 + w) * (1024 / SPLIT);

  short8 qfb[2][2][2];
  float ccb[2][2];

#define LOADQ(BUF, I0) do { \
    const unsigned short* qp_ = Qbase + ((I0) + l15) * DD + g * 8; \
    qfb[BUF][0][0] = *(const short8*)(qp_); \
    qfb[BUF][0][1] = *(const short8*)(qp_ + 32); \
    qfb[BUF][1][0] = *(const short8*)(qp_ + 16 * DD); \
    qfb[BUF][1][1] = *(const short8*)(qp_ + 16 * DD + 32); \
    ccb[BUF][0] = c2b[(I0) + l15]; \
    ccb[BUF][1] = c2b[(I0) + 16 + l15]; \
  } while (0)

  LOADQ(0, ibase);

#pragma unroll 2
  for (int itr = 0; itr < ITERS; ++itr) {
    const int cur = itr & 1, nxt = cur ^ 1;
    const int i0 = ibase + (itr << 5);

    // V B-frags for current iter (latency covered by QK+exp below)
    short8 vf[4];
#pragma unroll
    for (int ds = 0; ds < 4; ++ds)
      vf[ds] = *(const short8*)(Vbase + (ds * 16 + l15) * LQ + i0 + g * 8);

    // prefetch next iter's Q-frags + c2 (consumed next iteration)
    const int i0n = ibase + (((itr + 1 < ITERS) ? itr + 1 : itr) << 5);
    LOADQ(nxt, i0n);

    // T = K_j . Q_i^T ; P = exp2(T*C1 - c2[i]) ; pack hi16 pairs; LDS [i][jlow]
#pragma unroll
    for (int js = 0; js < 2; ++js) {
#pragma unroll
      for (int is = 0; is < 2; ++is) {
        f32x4 tt = __builtin_amdgcn_mfma_f32_16x16x32_bf16(
            ka[js][0], qfb[cur][is][0], (f32x4){0.f, 0.f, 0.f, 0.f}, 0, 0, 0);
        tt = __builtin_amdgcn_mfma_f32_16x16x32_bf16(ka[js][1], qfb[cur][is][1], tt, 0, 0, 0);
        const float cI = ccb[cur][is];
        const unsigned a0 = __builtin_bit_cast(unsigned, ex2(tt[0] * C1 - cI)) + 0x8000u;
        const unsigned a1 = __builtin_bit_cast(unsigned, ex2(tt[1] * C1 - cI)) + 0x8000u;
        const unsigned a2 = __builtin_bit_cast(unsigned, ex2(tt[2] * C1 - cI)) + 0x8000u;
        const unsigned a3 = __builtin_bit_cast(unsigned, ex2(tt[3] * C1 - cI)) + 0x8000u;
        uint2v uu;
        uu[0] = __builtin_amdgcn_perm(a1, a0, 0x07060302u);
        uu[1] = __builtin_amdgcn_perm(a3, a2, 0x07060302u);
        *(uint2v*)(&Pall[w][(js * 32 + is * 16 + l15) * 16 + g * 4]) = uu;
      }
    }

    // transpose-read all 4 P^T A-frags; wait inside asm, outputs carry dataflow
    unsigned long long r0, r1, r2, r3;
    const unsigned a = Pbase + g * 256 + l15 * 8;
    asm volatile(
        "ds_read_b64_tr_b16 %0, %4\n\t"
        "ds_read_b64_tr_b16 %1, %4 offset:128\n\t"
        "ds_read_b64_tr_b16 %2, %4 offset:1024\n\t"
        "ds_read_b64_tr_b16 %3, %4 offset:1152\n\t"
        "s_waitcnt lgkmcnt(0)"
        : "=&v"(r0), "=&v"(r1), "=&v"(r2), "=&v"(r3)
        : "v"(a) : "memory");
    union { unsigned long long u[2]; short8 s; } pa0, pa1;
    pa0.u[0] = r0; pa0.u[1] = r1;
    pa1.u[0] = r2; pa1.u[1] = r3;
#pragma unroll
    for (int ds = 0; ds < 4; ++ds)
      acc[0][ds] = __builtin_amdgcn_mfma_f32_16x16x32_bf16(pa0.s, vf[ds], acc[0][ds], 0, 0, 0);
#pragma unroll
    for (int ds = 0; ds < 4; ++ds)
      acc[1][ds] = __builtin_amdgcn_mfma_f32_16x16x32_bf16(pa1.s, vf[ds], acc[1][ds], 0, 0, 0);
  }
#undef LOADQ

  // per-wave partials -> LDS, cross-wave sum, fp32 store
#pragma unroll
  for (int js = 0; js < 2; ++js)
#pragma unroll
    for (int ds = 0; ds < 4; ++ds)
#pragma unroll
      for (int qq = 0; qq < 4; ++qq)
        red[w][(js * 16 + g * 4 + qq) * 64 + ds * 16 + l15] = acc[js][ds][qq];
  __syncthreads();

  const int jl = tid >> 3;
  const int d0 = (tid & 7) << 3;
  f32x4 o0, o1;
#pragma unroll
  for (int e = 0; e < 4; ++e) {
    const int idx = jl * 64 + d0 + e;
    o0[e] = red[0][idx] + red[1][idx] + red[2][idx] + red[3][idx];
  }
#pragma unroll
  for (int e = 0; e < 4; ++e) {
    const int idx = jl * 64 + d0 + 4 + e;
    o1[e] = red[0][idx] + red[1][idx] + red[2][idx] + red[3][idx];
  }
  float* op = dst + (SPLIT > 1 ? (size_t)cs * NTOT : 0) +
              (b * LQ + j0 + jl) * DD + d0;
  *(f32x4*)(op) = o0;
  *(f32x4*)(op + 4) = o1;
}

// ---------------------------------------------------------------------------
// reduce: out = sum over SPLIT chunks of partial
// ---------------------------------------------------------------------------
template<int SPLIT>
__global__ __launch_bounds__(256) void reduce_kernel(
    const float* __restrict__ part, float* __restrict__ out)
{
  const size_t idx = ((size_t)blockIdx.x * 256 + threadIdx.x) * 4;
  f32x4 s = *(const f32x4*)(part + idx);
#pragma unroll
  for (int c = 1; c < SPLIT; ++c) {
    const f32x4 t = *(const f32x4*)(part + idx + (size_t)c * NTOT);
    s[0] += t[0]; s[1] += t[1]; s[2] += t[2]; s[3] += t[3];
  }
  *(f32x4*)(out + idx) = s;
}

// ---------------------------------------------------------------------------
extern "C" void kernel_launch(void* const* d_in, const int* in_sizes, int n_in,
                              void* d_out, int out_size, void* d_ws, size_t ws_size,
                              hipStream_t stream) {
  const float* q = (const float*)d_in[0];
  const float* k = (const float*)d_in[1];
  const float* v = (const float*)d_in[2];

  unsigned short* Qb = (unsigned short*)d_ws;
  unsigned short* Kb = Qb + NTOT;
  unsigned short* Vt = Kb + NTOT;
  float* c2 = (float*)(Vt + NTOT);
  float* partial = c2 + (size_t)NB * LQ;
  float* outp = (float*)d_out;

  const size_t base = 3 * NTOT * 2 + (size_t)NB * LQ * 4;
  const size_t per = NTOT * 4;

  prep_kernel<<<NB * 256, 256, 0, stream>>>(q, k, v, Qb, Kb, Vt);
  stats_kernel<<<NB * 128, 512, 0, stream>>>(Qb, Kb, c2);

  if (ws_size >= base + 2 * per) {
    attn_out_kernel<2, 16><<<NB * 128 * 2, 256, 0, stream>>>(Qb, Kb, Vt, c2, partial);
    reduce_kernel<2><<<(int)(NTOT / 1024), 256, 0, stream>>>(partial, outp);
  } else {
    attn_out_kernel<1, 32><<<NB * 128, 256, 0, stream>>>(Qb, Kb, Vt, c2, outp);
  }
}

// Round 6
// 65.394 us; speedup vs baseline: 2.1552x; 1.7014x over previous
//
#include <hip/hip_runtime.h>
#include <hip/hip_bf16.h>

#define LQ 4096
#define DD 64
#define NB 4
#define NTOT ((size_t)NB * LQ * DD)

typedef __attribute__((ext_vector_type(4))) float f32x4;
typedef __attribute__((ext_vector_type(8))) short short8;
typedef __attribute__((ext_vector_type(2))) unsigned int uint2v;
typedef __attribute__((ext_vector_type(4))) unsigned short ushort4v;

static __device__ __forceinline__ unsigned short f2bf(float x) {
  __hip_bfloat16 h = __float2bfloat16(x);
  return __builtin_bit_cast(unsigned short, h);
}
static __device__ __forceinline__ float ex2(float x) { return __builtin_amdgcn_exp2f(x); }

// async global->LDS, 16B per lane, dest = ldsbase + lane*16
static __device__ __forceinline__ void gl_lds16(const unsigned short* g, unsigned short* l) {
  __builtin_amdgcn_global_load_lds(
      (const __attribute__((address_space(1))) unsigned int*)g,
      (__attribute__((address_space(3))) unsigned int*)l, 16, 0, 0);
}

// score scale folded into log2 domain: s2 = T * (0.125 * log2(e))
#define C1 0.18033688011112042f

// ---------------------------------------------------------------------------
// prep: pure cast Q,K,V -> bf16 (layouts unchanged, [b][i][d])
// grid: 1536 blocks of 256 (512 per array)
// ---------------------------------------------------------------------------
__global__ __launch_bounds__(256) void prep_kernel(
    const float* __restrict__ q, const float* __restrict__ k,
    const float* __restrict__ v,
    unsigned short* __restrict__ Qb, unsigned short* __restrict__ Kb,
    unsigned short* __restrict__ Vb)
{
  const int arr = blockIdx.x >> 9;
  const size_t off = (((size_t)(blockIdx.x & 511)) * 256 + threadIdx.x) * 8;
  const float* s = arr == 0 ? q : arr == 1 ? k : v;
  unsigned short* d = arr == 0 ? Qb : arr == 1 ? Kb : Vb;
  const f32x4 x0 = *(const f32x4*)(s + off);
  const f32x4 x1 = *(const f32x4*)(s + off + 4);
  ushort4v o0 = { f2bf(x0[0]), f2bf(x0[1]), f2bf(x0[2]), f2bf(x0[3]) };
  ushort4v o1 = { f2bf(x1[0]), f2bf(x1[1]), f2bf(x1[2]), f2bf(x1[3]) };
  *(ushort4v*)(d + off) = o0;
  *(ushort4v*)(d + off + 4) = o1;
}

// ---------------------------------------------------------------------------
// stats: lsum[b][i] += sum_{j in chunk} exp2(T[i,j]*C1)   (atomic over 8 chunks)
// grid: NB*32*8 blocks of 256. Block: i-tile 128 (4 waves x 32 i), j-chunk 512.
// K staged coalesced+XOR-swizzled into LDS, double-buffered.
// ---------------------------------------------------------------------------
__global__ __launch_bounds__(256, 4) void stats_kernel(
    const unsigned short* __restrict__ Qb, const unsigned short* __restrict__ Kb,
    float* __restrict__ lsum)
{
  __shared__ __align__(16) unsigned short stK[2][2048];
  const int bx = blockIdx.x;
  const int jc = bx & 7, it = (bx >> 3) & 31, b = bx >> 8;
  const int tid = threadIdx.x, w = tid >> 6, lane = tid & 63;
  const int l15 = lane & 15, g = lane >> 4;
  const int i0 = it * 128 + w * 32;
  const int jbase = jc * 512;
  const unsigned short* Kbase = Kb + (size_t)b * LQ * DD;

  // resident Q A-frags: A[m=i=l15][k=d]
  short8 aq[2][2];
#pragma unroll
  for (int is = 0; is < 2; ++is)
#pragma unroll
    for (int kh = 0; kh < 2; ++kh)
      aq[is][kh] = *(const short8*)(Qb + ((size_t)b * LQ + i0 + is * 16 + l15) * DD + kh * 32 + g * 8);

  float ls[2][4] = {{0.f, 0.f, 0.f, 0.f}, {0.f, 0.f, 0.f, 0.f}};

  const int srow = w * 8 + (lane >> 3);
  const int scol = ((lane & 7) ^ (lane >> 3)) << 3;

  gl_lds16(Kbase + (size_t)(jbase + srow) * DD + scol, &stK[0][w * 512]);
  __syncthreads();

  for (int itr = 0; itr < 16; ++itr) {
    const int cur = itr & 1, nxt = cur ^ 1;
    const int jn = jbase + ((itr + 1 < 16) ? itr + 1 : itr) * 32;
    gl_lds16(Kbase + (size_t)(jn + srow) * DD + scol, &stK[nxt][w * 512]);

    // K B-frags from swizzled LDS: B[n=j=l15][k=d]
    short8 kf[2][2];
#pragma unroll
    for (int jsub = 0; jsub < 2; ++jsub)
#pragma unroll
      for (int kh = 0; kh < 2; ++kh) {
        const int row = jsub * 16 + l15;
        kf[jsub][kh] = *(const short8*)(&stK[cur][row * 64 + (((kh * 4 + g) ^ (l15 & 7)) << 3)]);
      }
#pragma unroll
    for (int is = 0; is < 2; ++is)
#pragma unroll
      for (int jsub = 0; jsub < 2; ++jsub) {
        f32x4 tt = __builtin_amdgcn_mfma_f32_16x16x32_bf16(
            aq[is][0], kf[jsub][0], (f32x4){0.f, 0.f, 0.f, 0.f}, 0, 0, 0);
        tt = __builtin_amdgcn_mfma_f32_16x16x32_bf16(aq[is][1], kf[jsub][1], tt, 0, 0, 0);
#pragma unroll
        for (int qq = 0; qq < 4; ++qq) ls[is][qq] += ex2(tt[qq] * C1);
      }
    __syncthreads();
  }
  // sum over j-lanes (l15) within 16-lane groups
#pragma unroll
  for (int mask = 1; mask <= 8; mask <<= 1)
#pragma unroll
    for (int is = 0; is < 2; ++is)
#pragma unroll
      for (int qq = 0; qq < 4; ++qq) ls[is][qq] += __shfl_xor(ls[is][qq], mask, 64);
  if (l15 == 0) {
#pragma unroll
    for (int is = 0; is < 2; ++is)
#pragma unroll
      for (int qq = 0; qq < 4; ++qq)
        atomicAdd(&lsum[b * LQ + i0 + is * 16 + g * 4 + qq], ls[is][qq]);
  }
}

// ---------------------------------------------------------------------------
// attn_out: dst[j][d] (+chunk) = sum_{i in chunk} exp2(T[j,i]*C1 - log2 lsum[i]) * V[i][d]
// grid: NB*32*SPLIT blocks of 256. Block: j-tile 128 (4 waves x 32 j), i-chunk.
// Q+V staged coalesced into LDS (Q XOR-swizzled rows; V in [I][ds][4][16]
// subtile order for tr-reads), double-buffered, one barrier/iter.
// ---------------------------------------------------------------------------
template<int SPLIT, int ITERS>
__global__ __launch_bounds__(256, 4) void attn_out_kernel(
    const unsigned short* __restrict__ Qb, const unsigned short* __restrict__ Kb,
    const unsigned short* __restrict__ Vb, const float* __restrict__ lsum,
    float* __restrict__ dst)
{
  __shared__ __align__(16) unsigned short stage[2][4096]; // [buf][Q 2048 | V 2048] ushorts
  __shared__ __align__(16) unsigned short Pall[4 * 1088]; // per wave: 2 js x 8 sub x 68 ush

  const int bx = blockIdx.x;
  const int cs = bx & (SPLIT - 1);
  const int jt = (bx / SPLIT) & 31;
  const int b  = bx / (SPLIT * 32);
  const int tid = threadIdx.x, w = tid >> 6, lane = tid & 63;
  const int l15 = lane & 15, g = lane >> 4;
  const int j0 = jt * 128 + w * 32;

  const unsigned short* Qbase = Qb + (size_t)b * LQ * DD;
  const unsigned short* Vbase = Vb + (size_t)b * LQ * DD;
  const float* lsb = lsum + b * LQ;

  // resident K A-frags: A[m=j=l15][k=d]
  short8 ka[2][2];
#pragma unroll
  for (int js = 0; js < 2; ++js)
#pragma unroll
    for (int kh = 0; kh < 2; ++kh)
      ka[js][kh] = *(const short8*)(Kb + ((size_t)b * LQ + j0 + js * 16 + l15) * DD + kh * 32 + g * 8);

  f32x4 acc[2][4];
#pragma unroll
  for (int js = 0; js < 2; ++js)
#pragma unroll
    for (int ds = 0; ds < 4; ++ds) acc[js][ds] = (f32x4){0.f, 0.f, 0.f, 0.f};

  const int ibase = cs * (LQ / SPLIT);
  // staging source addressing (per-lane, row-coalesced)
  const int srow = w * 8 + (lane >> 3);
  const int scol = ((lane & 7) ^ (lane >> 3)) << 3;
  const int vsi = w * 8 + (lane >> 5) * 4 + ((lane & 7) >> 1);
  const int vsd = (((lane >> 3) & 3) << 4) + ((lane & 1) << 3);

  const unsigned vbyte0 = (unsigned)(size_t)&stage[0][2048];
  const unsigned vbyte1 = (unsigned)(size_t)&stage[1][2048];
  // FIX (round 5 bug): per-wave P stride is 1088 ushorts (2 js x 544), was 544
  // -> waves clobbered each other's js=1/js=0 regions.
  unsigned short* Pw = &Pall[w * 1088];
  const unsigned pbyte = (unsigned)(size_t)Pw;

#define STAGE(BUF, I0) do { \
    gl_lds16(Qbase + (size_t)((I0) + srow) * DD + scol, &stage[BUF][w * 512]); \
    gl_lds16(Vbase + (size_t)((I0) + vsi) * DD + vsd,  &stage[BUF][2048 + w * 512]); \
  } while (0)

  STAGE(0, ibase);
  __syncthreads();

  for (int itr = 0; itr < ITERS; ++itr) {
    const int cur = itr & 1, nxt = cur ^ 1;
    const int i0 = ibase + itr * 32;
    const int i0n = ibase + ((itr + 1 < ITERS) ? itr + 1 : itr) * 32;
    STAGE(nxt, i0n);

    // Q B-frags from swizzled LDS: B[n=i=l15][k=d]
    short8 qf[2][2];
#pragma unroll
    for (int is = 0; is < 2; ++is)
#pragma unroll
      for (int kh = 0; kh < 2; ++kh) {
        const int row = is * 16 + l15;
        qf[is][kh] = *(const short8*)(&stage[cur][row * 64 + (((kh * 4 + g) ^ (l15 & 7)) << 3)]);
      }

    // V B-frags via hw transpose read: B[n=d][k=i]
    unsigned long long v0, v1, v2, v3, v4, v5, v6, v7;
    const unsigned av = (cur ? vbyte1 : vbyte0) + g * 1024 + l15 * 8;
    asm volatile(
        "ds_read_b64_tr_b16 %0, %8\n\t"
        "ds_read_b64_tr_b16 %1, %8 offset:512\n\t"
        "ds_read_b64_tr_b16 %2, %8 offset:128\n\t"
        "ds_read_b64_tr_b16 %3, %8 offset:640\n\t"
        "ds_read_b64_tr_b16 %4, %8 offset:256\n\t"
        "ds_read_b64_tr_b16 %5, %8 offset:768\n\t"
        "ds_read_b64_tr_b16 %6, %8 offset:384\n\t"
        "ds_read_b64_tr_b16 %7, %8 offset:896\n\t"
        "s_waitcnt lgkmcnt(0)"
        : "=&v"(v0), "=&v"(v1), "=&v"(v2), "=&v"(v3),
          "=&v"(v4), "=&v"(v5), "=&v"(v6), "=&v"(v7)
        : "v"(av) : "memory");
    union U { unsigned long long u[2]; short8 s; };
    U vf0, vf1, vf2, vf3;
    vf0.u[0] = v0; vf0.u[1] = v1;
    vf1.u[0] = v2; vf1.u[1] = v3;
    vf2.u[0] = v4; vf2.u[1] = v5;
    vf3.u[0] = v6; vf3.u[1] = v7;

    const float cc0 = __builtin_amdgcn_logf(lsb[i0 + l15]);
    const float cc1 = __builtin_amdgcn_logf(lsb[i0 + 16 + l15]);

    // T = K_j . Q_i ; P = exp2(T*C1 - c2[i]) ; pack -> P LDS [js][i][jl]
#pragma unroll
    for (int js = 0; js < 2; ++js) {
#pragma unroll
      for (int is = 0; is < 2; ++is) {
        f32x4 tt = __builtin_amdgcn_mfma_f32_16x16x32_bf16(
            ka[js][0], qf[is][0], (f32x4){0.f, 0.f, 0.f, 0.f}, 0, 0, 0);
        tt = __builtin_amdgcn_mfma_f32_16x16x32_bf16(ka[js][1], qf[is][1], tt, 0, 0, 0);
        const float cI = is ? cc1 : cc0;
        const unsigned a0 = __builtin_bit_cast(unsigned, ex2(tt[0] * C1 - cI)) + 0x8000u;
        const unsigned a1 = __builtin_bit_cast(unsigned, ex2(tt[1] * C1 - cI)) + 0x8000u;
        const unsigned a2 = __builtin_bit_cast(unsigned, ex2(tt[2] * C1 - cI)) + 0x8000u;
        const unsigned a3 = __builtin_bit_cast(unsigned, ex2(tt[3] * C1 - cI)) + 0x8000u;
        uint2v uu;
        uu[0] = __builtin_amdgcn_perm(a1, a0, 0x07060302u);
        uu[1] = __builtin_amdgcn_perm(a3, a2, 0x07060302u);
        const int il = is * 16 + l15;
        *(uint2v*)(&Pw[js * 544 + (il >> 2) * 68 + (il & 3) * 16 + g * 4]) = uu;
      }
    }

    // P^T A-frags via tr-read (wait P writes first), then PV
    unsigned long long p0, p1, p2, p3;
    const unsigned ap = pbyte + g * 272 + l15 * 8;
    asm volatile(
        "s_waitcnt lgkmcnt(0)\n\t"
        "ds_read_b64_tr_b16 %0, %4\n\t"
        "ds_read_b64_tr_b16 %1, %4 offset:136\n\t"
        "ds_read_b64_tr_b16 %2, %4 offset:1088\n\t"
        "ds_read_b64_tr_b16 %3, %4 offset:1224\n\t"
        "s_waitcnt lgkmcnt(0)"
        : "=&v"(p0), "=&v"(p1), "=&v"(p2), "=&v"(p3)
        : "v"(ap) : "memory");
    U pa0, pa1;
    pa0.u[0] = p0; pa0.u[1] = p1;
    pa1.u[0] = p2; pa1.u[1] = p3;
#pragma unroll
    for (int ds = 0; ds < 4; ++ds)
      acc[0][ds] = __builtin_amdgcn_mfma_f32_16x16x32_bf16(pa0.s,
          ds == 0 ? vf0.s : ds == 1 ? vf1.s : ds == 2 ? vf2.s : vf3.s, acc[0][ds], 0, 0, 0);
#pragma unroll
    for (int ds = 0; ds < 4; ++ds)
      acc[1][ds] = __builtin_amdgcn_mfma_f32_16x16x32_bf16(pa1.s,
          ds == 0 ? vf0.s : ds == 1 ? vf1.s : ds == 2 ? vf2.s : vf3.s, acc[1][ds], 0, 0, 0);

    __syncthreads();
  }
#undef STAGE

  float* op = dst + (SPLIT > 1 ? (size_t)cs * NTOT : 0) + ((size_t)b * LQ + j0) * DD;
#pragma unroll
  for (int js = 0; js < 2; ++js)
#pragma unroll
    for (int ds = 0; ds < 4; ++ds)
#pragma unroll
      for (int qq = 0; qq < 4; ++qq)
        op[(js * 16 + g * 4 + qq) * 64 + ds * 16 + l15] = acc[js][ds][qq];
}

// ---------------------------------------------------------------------------
// reduce: out = sum over SPLIT chunks of partial
// ---------------------------------------------------------------------------
template<int SPLIT>
__global__ __launch_bounds__(256) void reduce_kernel(
    const float* __restrict__ part, float* __restrict__ out)
{
  const size_t idx = ((size_t)blockIdx.x * 256 + threadIdx.x) * 4;
  f32x4 s = *(const f32x4*)(part + idx);
#pragma unroll
  for (int c = 1; c < SPLIT; ++c) {
    const f32x4 t = *(const f32x4*)(part + idx + (size_t)c * NTOT);
    s[0] += t[0]; s[1] += t[1]; s[2] += t[2]; s[3] += t[3];
  }
  *(f32x4*)(out + idx) = s;
}

// ---------------------------------------------------------------------------
extern "C" void kernel_launch(void* const* d_in, const int* in_sizes, int n_in,
                              void* d_out, int out_size, void* d_ws, size_t ws_size,
                              hipStream_t stream) {
  const float* q = (const float*)d_in[0];
  const float* k = (const float*)d_in[1];
  const float* v = (const float*)d_in[2];

  unsigned short* Qb = (unsigned short*)d_ws;
  unsigned short* Kb = Qb + NTOT;
  unsigned short* Vb = Kb + NTOT;
  float* lsum = (float*)(Vb + NTOT);
  float* partial = lsum + (size_t)NB * LQ;
  float* outp = (float*)d_out;

  const size_t base = 3 * NTOT * 2 + (size_t)NB * LQ * 4;
  const size_t per = NTOT * 4;

  hipMemsetAsync(lsum, 0, (size_t)NB * LQ * sizeof(float), stream);
  prep_kernel<<<1536, 256, 0, stream>>>(q, k, v, Qb, Kb, Vb);
  stats_kernel<<<NB * 32 * 8, 256, 0, stream>>>(Qb, Kb, lsum);

  if (ws_size >= base + 8 * per) {
    attn_out_kernel<8, 16><<<NB * 32 * 8, 256, 0, stream>>>(Qb, Kb, Vb, lsum, partial);
    reduce_kernel<8><<<(int)(NTOT / 1024), 256, 0, stream>>>(partial, outp);
  } else if (ws_size >= base + 4 * per) {
    attn_out_kernel<4, 32><<<NB * 32 * 4, 256, 0, stream>>>(Qb, Kb, Vb, lsum, partial);
    reduce_kernel<4><<<(int)(NTOT / 1024), 256, 0, stream>>>(partial, outp);
  } else if (ws_size >= base + 2 * per) {
    attn_out_kernel<2, 64><<<NB * 32 * 2, 256, 0, stream>>>(Qb, Kb, Vb, lsum, partial);
    reduce_kernel<2><<<(int)(NTOT / 1024), 256, 0, stream>>>(partial, outp);
  } else {
    attn_out_kernel<1, 128><<<NB * 32, 256, 0, stream>>>(Qb, Kb, Vb, lsum, outp);
  }
}

// Round 7
// 64.964 us; speedup vs baseline: 2.1695x; 1.0066x over previous
//
#include <hip/hip_runtime.h>
#include <hip/hip_bf16.h>

#define LQ 4096
#define DD 64
#define NB 4
#define NTOT ((size_t)NB * LQ * DD)
#define NROW ((size_t)NB * LQ)

typedef __attribute__((ext_vector_type(4))) float f32x4;
typedef __attribute__((ext_vector_type(8))) short short8;
typedef __attribute__((ext_vector_type(2))) unsigned int uint2v;
typedef __attribute__((ext_vector_type(4))) unsigned short ushort4v;

static __device__ __forceinline__ unsigned short f2bf(float x) {
  __hip_bfloat16 h = __float2bfloat16(x);
  return __builtin_bit_cast(unsigned short, h);
}
static __device__ __forceinline__ float ex2(float x) { return __builtin_amdgcn_exp2f(x); }

// async global->LDS, 16B per lane, dest = ldsbase + lane*16
static __device__ __forceinline__ void gl_lds16(const unsigned short* g, unsigned short* l) {
  __builtin_amdgcn_global_load_lds(
      (const __attribute__((address_space(1))) unsigned int*)g,
      (__attribute__((address_space(3))) unsigned int*)l, 16, 0, 0);
}

// score scale folded into log2 domain: s2 = T * (0.125 * log2(e))
#define C1 0.18033688011112042f

// ---------------------------------------------------------------------------
// prep: pure cast Q,K,V -> bf16 (layouts unchanged, [b][i][d])
// ---------------------------------------------------------------------------
__global__ __launch_bounds__(256) void prep_kernel(
    const float* __restrict__ q, const float* __restrict__ k,
    const float* __restrict__ v,
    unsigned short* __restrict__ Qb, unsigned short* __restrict__ Kb,
    unsigned short* __restrict__ Vb)
{
  const int arr = blockIdx.x >> 9;
  const size_t off = (((size_t)(blockIdx.x & 511)) * 256 + threadIdx.x) * 8;
  const float* s = arr == 0 ? q : arr == 1 ? k : v;
  unsigned short* d = arr == 0 ? Qb : arr == 1 ? Kb : Vb;
  const f32x4 x0 = *(const f32x4*)(s + off);
  const f32x4 x1 = *(const f32x4*)(s + off + 4);
  ushort4v o0 = { f2bf(x0[0]), f2bf(x0[1]), f2bf(x0[2]), f2bf(x0[3]) };
  ushort4v o1 = { f2bf(x1[0]), f2bf(x1[1]), f2bf(x1[2]), f2bf(x1[3]) };
  *(ushort4v*)(d + off) = o0;
  *(ushort4v*)(d + off + 4) = o1;
}

// ---------------------------------------------------------------------------
// stats: part_ls[jc][b*LQ + i] = sum_{j in chunk jc} exp2(T[i,j]*C1)
// (pure stores, no init / no atomics). grid: NB*32*8 blocks of 256.
// ---------------------------------------------------------------------------
__global__ __launch_bounds__(256, 4) void stats_kernel(
    const unsigned short* __restrict__ Qb, const unsigned short* __restrict__ Kb,
    float* __restrict__ part_ls)
{
  __shared__ __align__(16) unsigned short stK[2][2048];
  const int bx = blockIdx.x;
  const int jc = bx & 7, it = (bx >> 3) & 31, b = bx >> 8;
  const int tid = threadIdx.x, w = tid >> 6, lane = tid & 63;
  const int l15 = lane & 15, g = lane >> 4;
  const int i0 = it * 128 + w * 32;
  const int jbase = jc * 512;
  const unsigned short* Kbase = Kb + (size_t)b * LQ * DD;

  // resident Q A-frags: A[m=i=l15][k=d]
  short8 aq[2][2];
#pragma unroll
  for (int is = 0; is < 2; ++is)
#pragma unroll
    for (int kh = 0; kh < 2; ++kh)
      aq[is][kh] = *(const short8*)(Qb + ((size_t)b * LQ + i0 + is * 16 + l15) * DD + kh * 32 + g * 8);

  float ls[2][4] = {{0.f, 0.f, 0.f, 0.f}, {0.f, 0.f, 0.f, 0.f}};

  const int srow = w * 8 + (lane >> 3);
  const int scol = ((lane & 7) ^ (lane >> 3)) << 3;

  gl_lds16(Kbase + (size_t)(jbase + srow) * DD + scol, &stK[0][w * 512]);
  __syncthreads();

  for (int itr = 0; itr < 16; ++itr) {
    const int cur = itr & 1, nxt = cur ^ 1;
    const int jn = jbase + ((itr + 1 < 16) ? itr + 1 : itr) * 32;
    gl_lds16(Kbase + (size_t)(jn + srow) * DD + scol, &stK[nxt][w * 512]);

    // K B-frags from swizzled LDS: B[n=j=l15][k=d]
    short8 kf[2][2];
#pragma unroll
    for (int jsub = 0; jsub < 2; ++jsub)
#pragma unroll
      for (int kh = 0; kh < 2; ++kh) {
        const int row = jsub * 16 + l15;
        kf[jsub][kh] = *(const short8*)(&stK[cur][row * 64 + (((kh * 4 + g) ^ (l15 & 7)) << 3)]);
      }
#pragma unroll
    for (int is = 0; is < 2; ++is)
#pragma unroll
      for (int jsub = 0; jsub < 2; ++jsub) {
        f32x4 tt = __builtin_amdgcn_mfma_f32_16x16x32_bf16(
            aq[is][0], kf[jsub][0], (f32x4){0.f, 0.f, 0.f, 0.f}, 0, 0, 0);
        tt = __builtin_amdgcn_mfma_f32_16x16x32_bf16(aq[is][1], kf[jsub][1], tt, 0, 0, 0);
#pragma unroll
        for (int qq = 0; qq < 4; ++qq) ls[is][qq] += ex2(tt[qq] * C1);
      }
    __syncthreads();
  }
  // sum over j-lanes (l15) within 16-lane groups
#pragma unroll
  for (int mask = 1; mask <= 8; mask <<= 1)
#pragma unroll
    for (int is = 0; is < 2; ++is)
#pragma unroll
      for (int qq = 0; qq < 4; ++qq) ls[is][qq] += __shfl_xor(ls[is][qq], mask, 64);
  if (l15 == 0) {
#pragma unroll
    for (int is = 0; is < 2; ++is)
#pragma unroll
      for (int qq = 0; qq < 4; ++qq)
        part_ls[(size_t)jc * NROW + b * LQ + i0 + is * 16 + g * 4 + qq] = ls[is][qq];
  }
}

// ---------------------------------------------------------------------------
// combine: c2[x] = log2( sum_{jc<8} part_ls[jc][x] )   (64 blocks of 256)
// ---------------------------------------------------------------------------
__global__ __launch_bounds__(256) void combine_kernel(
    const float* __restrict__ part_ls, float* __restrict__ c2)
{
  const int x = blockIdx.x * 256 + threadIdx.x;
  float s = 0.f;
#pragma unroll
  for (int jc = 0; jc < 8; ++jc) s += part_ls[(size_t)jc * NROW + x];
  c2[x] = __builtin_amdgcn_logf(s);  // v_log_f32 = log2
}

// ---------------------------------------------------------------------------
// attn_out: dst[j][d] (+chunk) = sum_{i in chunk} exp2(T[j,i]*C1 - c2[i]) * V[i][d]
// grid: NB*32*SPLIT blocks of 256. Block: j-tile 128 (4 waves x 32 j), i-chunk.
// Q+V staged coalesced into LDS (Q XOR-swizzled rows; V in [I][ds][4][16]
// subtile order for tr-reads), double-buffered, one barrier/iter.
// ---------------------------------------------------------------------------
template<int SPLIT, int ITERS>
__global__ __launch_bounds__(256, 4) void attn_out_kernel(
    const unsigned short* __restrict__ Qb, const unsigned short* __restrict__ Kb,
    const unsigned short* __restrict__ Vb, const float* __restrict__ c2g,
    float* __restrict__ dst)
{
  __shared__ __align__(16) unsigned short stage[2][4096]; // [buf][Q 2048 | V 2048] ushorts
  __shared__ __align__(16) unsigned short Pall[4 * 1088]; // per wave: 2 js x 8 sub x 68 ush

  const int bx = blockIdx.x;
  const int cs = bx & (SPLIT - 1);
  const int jt = (bx / SPLIT) & 31;
  const int b  = bx / (SPLIT * 32);
  const int tid = threadIdx.x, w = tid >> 6, lane = tid & 63;
  const int l15 = lane & 15, g = lane >> 4;
  const int j0 = jt * 128 + w * 32;

  const unsigned short* Qbase = Qb + (size_t)b * LQ * DD;
  const unsigned short* Vbase = Vb + (size_t)b * LQ * DD;
  const float* c2b = c2g + b * LQ;

  // resident K A-frags: A[m=j=l15][k=d]
  short8 ka[2][2];
#pragma unroll
  for (int js = 0; js < 2; ++js)
#pragma unroll
    for (int kh = 0; kh < 2; ++kh)
      ka[js][kh] = *(const short8*)(Kb + ((size_t)b * LQ + j0 + js * 16 + l15) * DD + kh * 32 + g * 8);

  f32x4 acc[2][4];
#pragma unroll
  for (int js = 0; js < 2; ++js)
#pragma unroll
    for (int ds = 0; ds < 4; ++ds) acc[js][ds] = (f32x4){0.f, 0.f, 0.f, 0.f};

  const int ibase = cs * (LQ / SPLIT);
  // staging source addressing (per-lane, row-coalesced)
  const int srow = w * 8 + (lane >> 3);
  const int scol = ((lane & 7) ^ (lane >> 3)) << 3;
  const int vsi = w * 8 + (lane >> 5) * 4 + ((lane & 7) >> 1);
  const int vsd = (((lane >> 3) & 3) << 4) + ((lane & 1) << 3);

  const unsigned vbyte0 = (unsigned)(size_t)&stage[0][2048];
  const unsigned vbyte1 = (unsigned)(size_t)&stage[1][2048];
  unsigned short* Pw = &Pall[w * 1088];
  const unsigned pbyte = (unsigned)(size_t)Pw;

#define STAGE(BUF, I0) do { \
    gl_lds16(Qbase + (size_t)((I0) + srow) * DD + scol, &stage[BUF][w * 512]); \
    gl_lds16(Vbase + (size_t)((I0) + vsi) * DD + vsd,  &stage[BUF][2048 + w * 512]); \
  } while (0)

  STAGE(0, ibase);
  __syncthreads();

  for (int itr = 0; itr < ITERS; ++itr) {
    const int cur = itr & 1, nxt = cur ^ 1;
    const int i0 = ibase + itr * 32;
    const int i0n = ibase + ((itr + 1 < ITERS) ? itr + 1 : itr) * 32;
    STAGE(nxt, i0n);

    // Q B-frags from swizzled LDS: B[n=i=l15][k=d]
    short8 qf[2][2];
#pragma unroll
    for (int is = 0; is < 2; ++is)
#pragma unroll
      for (int kh = 0; kh < 2; ++kh) {
        const int row = is * 16 + l15;
        qf[is][kh] = *(const short8*)(&stage[cur][row * 64 + (((kh * 4 + g) ^ (l15 & 7)) << 3)]);
      }

    // V B-frags via hw transpose read: B[n=d][k=i]
    unsigned long long v0, v1, v2, v3, v4, v5, v6, v7;
    const unsigned av = (cur ? vbyte1 : vbyte0) + g * 1024 + l15 * 8;
    asm volatile(
        "ds_read_b64_tr_b16 %0, %8\n\t"
        "ds_read_b64_tr_b16 %1, %8 offset:512\n\t"
        "ds_read_b64_tr_b16 %2, %8 offset:128\n\t"
        "ds_read_b64_tr_b16 %3, %8 offset:640\n\t"
        "ds_read_b64_tr_b16 %4, %8 offset:256\n\t"
        "ds_read_b64_tr_b16 %5, %8 offset:768\n\t"
        "ds_read_b64_tr_b16 %6, %8 offset:384\n\t"
        "ds_read_b64_tr_b16 %7, %8 offset:896\n\t"
        "s_waitcnt lgkmcnt(0)"
        : "=&v"(v0), "=&v"(v1), "=&v"(v2), "=&v"(v3),
          "=&v"(v4), "=&v"(v5), "=&v"(v6), "=&v"(v7)
        : "v"(av) : "memory");
    union U { unsigned long long u[2]; short8 s; };
    U vf0, vf1, vf2, vf3;
    vf0.u[0] = v0; vf0.u[1] = v1;
    vf1.u[0] = v2; vf1.u[1] = v3;
    vf2.u[0] = v4; vf2.u[1] = v5;
    vf3.u[0] = v6; vf3.u[1] = v7;

    const float cc0 = c2b[i0 + l15];
    const float cc1 = c2b[i0 + 16 + l15];

    // T = K_j . Q_i ; P = exp2(T*C1 - c2[i]) ; pack -> P LDS [js][i][jl]
#pragma unroll
    for (int js = 0; js < 2; ++js) {
#pragma unroll
      for (int is = 0; is < 2; ++is) {
        f32x4 tt = __builtin_amdgcn_mfma_f32_16x16x32_bf16(
            ka[js][0], qf[is][0], (f32x4){0.f, 0.f, 0.f, 0.f}, 0, 0, 0);
        tt = __builtin_amdgcn_mfma_f32_16x16x32_bf16(ka[js][1], qf[is][1], tt, 0, 0, 0);
        const float cI = is ? cc1 : cc0;
        const unsigned a0 = __builtin_bit_cast(unsigned, ex2(tt[0] * C1 - cI)) + 0x8000u;
        const unsigned a1 = __builtin_bit_cast(unsigned, ex2(tt[1] * C1 - cI)) + 0x8000u;
        const unsigned a2 = __builtin_bit_cast(unsigned, ex2(tt[2] * C1 - cI)) + 0x8000u;
        const unsigned a3 = __builtin_bit_cast(unsigned, ex2(tt[3] * C1 - cI)) + 0x8000u;
        uint2v uu;
        uu[0] = __builtin_amdgcn_perm(a1, a0, 0x07060302u);
        uu[1] = __builtin_amdgcn_perm(a3, a2, 0x07060302u);
        const int il = is * 16 + l15;
        *(uint2v*)(&Pw[js * 544 + (il >> 2) * 68 + (il & 3) * 16 + g * 4]) = uu;
      }
    }

    // P^T A-frags via tr-read (wait P writes first), then PV
    unsigned long long p0, p1, p2, p3;
    const unsigned ap = pbyte + g * 272 + l15 * 8;
    asm volatile(
        "s_waitcnt lgkmcnt(0)\n\t"
        "ds_read_b64_tr_b16 %0, %4\n\t"
        "ds_read_b64_tr_b16 %1, %4 offset:136\n\t"
        "ds_read_b64_tr_b16 %2, %4 offset:1088\n\t"
        "ds_read_b64_tr_b16 %3, %4 offset:1224\n\t"
        "s_waitcnt lgkmcnt(0)"
        : "=&v"(p0), "=&v"(p1), "=&v"(p2), "=&v"(p3)
        : "v"(ap) : "memory");
    U pa0, pa1;
    pa0.u[0] = p0; pa0.u[1] = p1;
    pa1.u[0] = p2; pa1.u[1] = p3;
#pragma unroll
    for (int ds = 0; ds < 4; ++ds)
      acc[0][ds] = __builtin_amdgcn_mfma_f32_16x16x32_bf16(pa0.s,
          ds == 0 ? vf0.s : ds == 1 ? vf1.s : ds == 2 ? vf2.s : vf3.s, acc[0][ds], 0, 0, 0);
#pragma unroll
    for (int ds = 0; ds < 4; ++ds)
      acc[1][ds] = __builtin_amdgcn_mfma_f32_16x16x32_bf16(pa1.s,
          ds == 0 ? vf0.s : ds == 1 ? vf1.s : ds == 2 ? vf2.s : vf3.s, acc[1][ds], 0, 0, 0);

    __syncthreads();
  }
#undef STAGE

  float* op = dst + (SPLIT > 1 ? (size_t)cs * NTOT : 0) + ((size_t)b * LQ + j0) * DD;
#pragma unroll
  for (int js = 0; js < 2; ++js)
#pragma unroll
    for (int ds = 0; ds < 4; ++ds)
#pragma unroll
      for (int qq = 0; qq < 4; ++qq)
        op[(js * 16 + g * 4 + qq) * 64 + ds * 16 + l15] = acc[js][ds][qq];
}

// ---------------------------------------------------------------------------
// reduce: out = sum over SPLIT chunks of partial
// ---------------------------------------------------------------------------
template<int SPLIT>
__global__ __launch_bounds__(256) void reduce_kernel(
    const float* __restrict__ part, float* __restrict__ out)
{
  const size_t idx = ((size_t)blockIdx.x * 256 + threadIdx.x) * 4;
  f32x4 s = *(const f32x4*)(part + idx);
#pragma unroll
  for (int c = 1; c < SPLIT; ++c) {
    const f32x4 t = *(const f32x4*)(part + idx + (size_t)c * NTOT);
    s[0] += t[0]; s[1] += t[1]; s[2] += t[2]; s[3] += t[3];
  }
  *(f32x4*)(out + idx) = s;
}

// ---------------------------------------------------------------------------
extern "C" void kernel_launch(void* const* d_in, const int* in_sizes, int n_in,
                              void* d_out, int out_size, void* d_ws, size_t ws_size,
                              hipStream_t stream) {
  const float* q = (const float*)d_in[0];
  const float* k = (const float*)d_in[1];
  const float* v = (const float*)d_in[2];

  unsigned short* Qb = (unsigned short*)d_ws;
  unsigned short* Kb = Qb + NTOT;
  unsigned short* Vb = Kb + NTOT;
  float* c2 = (float*)(Vb + NTOT);
  float* part_ls = c2 + NROW;
  float* partial = part_ls + 8 * NROW;
  float* outp = (float*)d_out;

  const size_t base = 3 * NTOT * 2 + NROW * 4 * 9;
  const size_t per = NTOT * 4;

  prep_kernel<<<1536, 256, 0, stream>>>(q, k, v, Qb, Kb, Vb);
  stats_kernel<<<NB * 32 * 8, 256, 0, stream>>>(Qb, Kb, part_ls);
  combine_kernel<<<(int)(NROW / 256), 256, 0, stream>>>(part_ls, c2);

  if (ws_size >= base + 8 * per) {
    attn_out_kernel<8, 16><<<NB * 32 * 8, 256, 0, stream>>>(Qb, Kb, Vb, c2, partial);
    reduce_kernel<8><<<(int)(NTOT / 1024), 256, 0, stream>>>(partial, outp);
  } else if (ws_size >= base + 4 * per) {
    attn_out_kernel<4, 32><<<NB * 32 * 4, 256, 0, stream>>>(Qb, Kb, Vb, c2, partial);
    reduce_kernel<4><<<(int)(NTOT / 1024), 256, 0, stream>>>(partial, outp);
  } else if (ws_size >= base + 2 * per) {
    attn_out_kernel<2, 64><<<NB * 32 * 2, 256, 0, stream>>>(Qb, Kb, Vb, c2, partial);
    reduce_kernel<2><<<(int)(NTOT / 1024), 256, 0, stream>>>(partial, outp);
  } else {
    attn_out_kernel<1, 128><<<NB * 32, 256, 0, stream>>>(Qb, Kb, Vb, c2, outp);
  }
}